// Round 1
// baseline (254.919 us; speedup 1.0000x reference)
//
#include <hip/hip_runtime.h>
#include <hip/hip_bf16.h>
#include <stdint.h>
#include <stddef.h>

typedef __bf16 bf16;
typedef float f32x4 __attribute__((ext_vector_type(4)));
typedef bf16 bf16x8 __attribute__((ext_vector_type(8)));
typedef bf16 bf16x4 __attribute__((ext_vector_type(4)));

#define MROWS 8192     // rows of every GEMM output
#define NOUT 256       // cols of every GEMM output
#define BM 32          // block tile rows -> grid = 256 blocks = 1/CU
#define BK 128         // K-step
#define NTHREADS 512   // 8 waves

#define LDS_A_BYTES (BM * BK * 2)    // 8 KiB
#define LDS_B_BYTES (NOUT * BK * 2)  // 64 KiB
#define LDS_BUF_BYTES (LDS_A_BYTES + LDS_B_BYTES)  // 72 KiB, x2 = 144 KiB

__device__ __forceinline__ void glds16(const void* g, const void* l) {
  __builtin_amdgcn_global_load_lds(
      (const __attribute__((address_space(1))) void*)g,
      (__attribute__((address_space(3))) void*)l, 16, 0, 0);
}

// C = A(fp32, lda) @ B^T(bf16, [NOUT][K])  with fused epilogue.
// OUTT=true: write bf16 transposed Ct[n][m] (optionally scaled by filt[m]).
// OUTT=false: write fp32 C[m][n].
template <bool SCALE, bool OUTT>
__global__ __launch_bounds__(NTHREADS, 1) void gemm_fused(
    const float* __restrict__ A, const bf16* __restrict__ Bt,
    const float* __restrict__ filt, void* __restrict__ outp,
    const int K, const int lda) {
  __shared__ char lds[2][LDS_BUF_BYTES];
  const int t = threadIdx.x;
  const int w = t >> 6;   // wave 0..7, owns 32 output cols
  const int l = t & 63;
  const int m0 = blockIdx.x * BM;

  // ---- A staging map: thread -> (row, 8-float col block), fp32 -> bf16, swizzled store
  const int ar = t >> 4;     // 0..31
  const int acb = t & 15;    // 8-float chunk
  const float* gA = A + (size_t)(m0 + ar) * (size_t)lda + acb * 8;
  const int a_lds_off = (ar * (BK * 2) + acb * 16) ^ ((ar & 7) << 4);

  // ---- B staging map: 8 x global_load_lds(16B) per wave per K-step.
  // LDS dest linear; global source pre-swizzled so swizzled ds_read is correct.
  const char* gB[8];
  int b_lds_off[8];
#pragma unroll
  for (int i = 0; i < 8; ++i) {
    const int sbase = (w * 8 + i) * 1024;          // wave-uniform LDS chunk base
    const int n = (sbase >> 8) + (l >> 4);         // B row (0..255) this lane feeds
    const int srcoff = ((l & 15) * 16) ^ ((n & 7) << 4);
    gB[i] = (const char*)Bt + (size_t)n * (size_t)(K * 2) + srcoff;
    b_lds_off[i] = LDS_A_BYTES + sbase;
  }

  // ---- fragment read offsets (XOR-swizzled)
  int aoff[2][4], boff[2][4];
#pragma unroll
  for (int af = 0; af < 2; ++af)
#pragma unroll
    for (int ak = 0; ak < 4; ++ak) {
      const int r = af * 16 + (l & 15);
      const int kb = ak * 64 + (l >> 4) * 16;
      aoff[af][ak] = (r * (BK * 2) + kb) ^ ((r & 7) << 4);
    }
#pragma unroll
  for (int bfi = 0; bfi < 2; ++bfi)
#pragma unroll
    for (int ak = 0; ak < 4; ++ak) {
      const int n = w * 32 + bfi * 16 + (l & 15);
      const int kb = ak * 64 + (l >> 4) * 16;
      boff[bfi][ak] = LDS_A_BYTES + ((n * (BK * 2) + kb) ^ ((n & 7) << 4));
    }

  f32x4 acc[2][2] = {};
  const int NT = K / BK;

  auto stage = [&](char* buf, int k0) {
    const f32x4* pa = (const f32x4*)(gA + k0);
    f32x4 v0 = __builtin_nontemporal_load(pa);
    f32x4 v1 = __builtin_nontemporal_load(pa + 1);
#pragma unroll
    for (int i = 0; i < 8; ++i)
      glds16(gB[i] + (size_t)k0 * 2, buf + b_lds_off[i]);
    bf16x8 pk;
#pragma unroll
    for (int j = 0; j < 4; ++j) {
      pk[j] = (bf16)v0[j];
      pk[j + 4] = (bf16)v1[j];
    }
    *(bf16x8*)(buf + a_lds_off) = pk;
  };

  stage(lds[0], 0);
  __syncthreads();
  int buf = 0;
  for (int ts = 0; ts < NT; ++ts) {
    if (ts + 1 < NT) stage(lds[buf ^ 1], (ts + 1) * BK);
    const char* bb = lds[buf];
    bf16x8 afr[2][4], bfr[2][4];
#pragma unroll
    for (int af = 0; af < 2; ++af)
#pragma unroll
      for (int ak = 0; ak < 4; ++ak)
        afr[af][ak] = *(const bf16x8*)(bb + aoff[af][ak]);
#pragma unroll
    for (int bfi = 0; bfi < 2; ++bfi)
#pragma unroll
      for (int ak = 0; ak < 4; ++ak)
        bfr[bfi][ak] = *(const bf16x8*)(bb + boff[bfi][ak]);
#pragma unroll
    for (int ak = 0; ak < 4; ++ak)
#pragma unroll
      for (int af = 0; af < 2; ++af)
#pragma unroll
        for (int bfi = 0; bfi < 2; ++bfi)
          acc[af][bfi] = __builtin_amdgcn_mfma_f32_16x16x32_bf16(
              afr[af][ak], bfr[bfi][ak], acc[af][bfi], 0, 0, 0);
    __syncthreads();
    buf ^= 1;
  }

  // ---- epilogue (C/D layout: col = lane&15, row = (lane>>4)*4 + reg)
#pragma unroll
  for (int af = 0; af < 2; ++af)
#pragma unroll
    for (int bfi = 0; bfi < 2; ++bfi) {
      const int mb = m0 + af * 16 + (l >> 4) * 4;
      const int n = w * 32 + bfi * 16 + (l & 15);
      f32x4 v = acc[af][bfi];
      if (SCALE) {
#pragma unroll
        for (int j = 0; j < 4; ++j) v[j] *= filt[mb + j];
      }
      if (OUTT) {
        bf16x4 pv;
#pragma unroll
        for (int j = 0; j < 4; ++j) pv[j] = (bf16)v[j];
        *(bf16x4*)((bf16*)outp + (size_t)n * MROWS + mb) = pv;
      } else {
        float* po = (float*)outp + (size_t)mb * NOUT + n;
#pragma unroll
        for (int j = 0; j < 4; ++j) po[(size_t)j * NOUT] = v[j];
      }
    }
}

// W [256][256] fp32 -> Wt [n][k] bf16 (transpose + convert)
__global__ void prep_wt(const float* __restrict__ W, bf16* __restrict__ Wt) {
  const int k = blockIdx.x;   // row of W
  const int n = threadIdx.x;  // col of W
  Wt[(size_t)n * 256 + k] = (bf16)W[(size_t)k * 256 + n];
}

extern "C" void kernel_launch(void* const* d_in, const int* in_sizes, int n_in,
                              void* d_out, int out_size, void* d_ws, size_t ws_size,
                              hipStream_t stream) {
  const float* features = (const float*)d_in[0];      // [8192][256]
  const float* wavelets = (const float*)d_in[1];      // [8192][8192]
  const float* wavelets_inv = (const float*)d_in[2];  // [8192][8192]
  const float* W = (const float*)d_in[3];             // [256][256]
  const float* filt = (const float*)d_in[4];          // [8192]
  float* out = (float*)d_out;

  char* ws = (char*)d_ws;
  bf16* Wt = (bf16*)ws;                          // 128 KiB
  bf16* Tt = (bf16*)(ws + 131072);               // 4 MiB: (features@W)^T [256][8192]
  bf16* Ft = (bf16*)(ws + 131072 + 4194304);     // 4 MiB: (filt*spectral)^T [256][8192]

  prep_wt<<<256, 256, 0, stream>>>(W, Wt);
  // T^T = (features @ W)^T
  gemm_fused<false, true><<<256, NTHREADS, 0, stream>>>(features, Wt, nullptr, Tt, 256, 256);
  // F^T = (diag(filt) @ (wavelets_inv @ T))^T
  gemm_fused<true, true><<<256, NTHREADS, 0, stream>>>(wavelets_inv, Tt, filt, Ft, 8192, 8192);
  // out = wavelets @ F
  gemm_fused<false, false><<<256, NTHREADS, 0, stream>>>(wavelets, Ft, nullptr, out, 8192, 8192);
}

// Round 2
// 229.520 us; speedup vs baseline: 1.1107x; 1.1107x over previous
//
#include <hip/hip_runtime.h>
#include <hip/hip_bf16.h>
#include <stdint.h>
#include <stddef.h>

typedef __bf16 bf16;
typedef float f32x4 __attribute__((ext_vector_type(4)));
typedef bf16 bf16x8 __attribute__((ext_vector_type(8)));
typedef bf16 bf16x4 __attribute__((ext_vector_type(4)));

#define MROWS 8192
#define NOUT 256
#define BM 32
#define BK 128
#define NTHREADS 512

#define LDS_A_BYTES (BM * BK * 2)                  // 8 KiB (bf16)
#define LDS_B_BYTES (NOUT * BK * 2)                // 64 KiB
#define LDS_BUF_BYTES (LDS_A_BYTES + LDS_B_BYTES)  // 72 KiB, x2 = 144 KiB

#define SCHED0 __builtin_amdgcn_sched_barrier(0)
#define SBAR __builtin_amdgcn_s_barrier()

__device__ __forceinline__ void glds16(const void* g, const void* l) {
  __builtin_amdgcn_global_load_lds(
      (const __attribute__((address_space(1))) void*)g,
      (__attribute__((address_space(3))) void*)l, 16, 0, 0);
}

// C = A(fp32, lda) @ B^T(bf16 [NOUT][K]) with fused epilogue.
// OUTT: write bf16 transposed Ct[n][m] (opt. scaled by filt[m]); else fp32 C[m][n].
template <bool SCALE, bool OUTT>
__global__ __launch_bounds__(NTHREADS, 1) void gemm_fused(
    const float* __restrict__ A, const bf16* __restrict__ Bt,
    const float* __restrict__ filt, void* __restrict__ outp,
    const int K, const int lda) {
  __shared__ char lds[2][LDS_BUF_BYTES];
  const int t = threadIdx.x;
  const int w = t >> 6;
  const int l = t & 63;
  const int m0 = blockIdx.x * BM;
  const int NT = K / BK;

  // ---- A staging map: thread -> (row, 8-float chunk); cvt to bf16, swizzled ds_write
  const int ar = t >> 4;
  const int acb = t & 15;
  const float* gA = A + (size_t)(m0 + ar) * (size_t)lda + acb * 8;
  const int a_lds_off = (ar * (BK * 2) + acb * 16) ^ ((ar & 7) << 4);

  // ---- B staging: 8 x global_load_lds(16B)/wave/step; linear LDS dest,
  //      pre-swizzled global source (Guideline 21)
  const char* gB[8];
  int b_lds_off[8];
#pragma unroll
  for (int i = 0; i < 8; ++i) {
    const int sbase = (w * 8 + i) * 1024;
    const int n = (sbase >> 8) + (l >> 4);
    const int srcoff = ((l & 15) * 16) ^ ((n & 7) << 4);
    gB[i] = (const char*)Bt + (size_t)n * (size_t)(K * 2) + srcoff;
    b_lds_off[i] = LDS_A_BYTES + sbase;
  }

  // ---- fragment read offsets (XOR-swizzled)
  int aoff[2][4], boff[2][4];
#pragma unroll
  for (int af = 0; af < 2; ++af)
#pragma unroll
    for (int ak = 0; ak < 4; ++ak) {
      const int r = af * 16 + (l & 15);
      const int kb = ak * 64 + (l >> 4) * 16;
      aoff[af][ak] = (r * (BK * 2) + kb) ^ ((r & 7) << 4);
    }
#pragma unroll
  for (int bfi = 0; bfi < 2; ++bfi)
#pragma unroll
    for (int ak = 0; ak < 4; ++ak) {
      const int n = w * 32 + bfi * 16 + (l & 15);
      const int kb = ak * 64 + (l >> 4) * 16;
      boff[bfi][ak] = LDS_A_BYTES + ((n * (BK * 2) + kb) ^ ((n & 7) << 4));
    }

  f32x4 acc[2][2] = {};

  // ================= prologue =================
  // A(0) -> S0, B(0) glds -> lds[0], A(1) -> S1; cvt+write A(0); counted drain; barrier.
  f32x4 aS0a = __builtin_nontemporal_load((const f32x4*)gA);
  f32x4 aS0b = __builtin_nontemporal_load((const f32x4*)gA + 1);
  SCHED0;
#pragma unroll
  for (int i = 0; i < 8; ++i) glds16(gB[i], lds[0] + b_lds_off[i]);
  SCHED0;
  f32x4 aS1a = __builtin_nontemporal_load((const f32x4*)(gA + BK));
  f32x4 aS1b = __builtin_nontemporal_load((const f32x4*)(gA + BK) + 1);
  SCHED0;
  {
    bf16x8 pk;
#pragma unroll
    for (int j = 0; j < 4; ++j) {
      pk[j] = (bf16)aS0a[j];
      pk[j + 4] = (bf16)aS0b[j];
    }
    *(bf16x8*)(lds[0] + a_lds_off) = pk;
  }
  asm volatile("s_waitcnt vmcnt(2) lgkmcnt(0)" ::: "memory");  // B(0)+write done; A(1) in flight
  SBAR;
  SCHED0;

  // ================= main loop (unrolled x2 for static reg-set indexing) =================
  // Iter t: read lds[p]; issue B(t+1)->lds[p^1], A(t+2)->AL; MFMA; cvt AW (=A(t+1)) -> lds[p^1];
  // counted wait (leave A(t+2) in flight); barrier.
#define BODY(TS, CUR, NXT, AW0, AW1, AL0, AL1)                                \
  {                                                                           \
    const char* bb = (CUR);                                                   \
    bf16x8 afr[2][4], bfr[2][4];                                              \
    _Pragma("unroll") for (int af = 0; af < 2; ++af)                          \
        _Pragma("unroll") for (int ak = 0; ak < 4; ++ak)                      \
            afr[af][ak] = *(const bf16x8*)(bb + aoff[af][ak]);                \
    _Pragma("unroll") for (int bfi = 0; bfi < 2; ++bfi)                       \
        _Pragma("unroll") for (int ak = 0; ak < 4; ++ak)                      \
            bfr[bfi][ak] = *(const bf16x8*)(bb + boff[bfi][ak]);              \
    SCHED0;                                                                   \
    const int kb1 = (((TS) + 1) < NT ? ((TS) + 1) : 0) * BK;                  \
    _Pragma("unroll") for (int i = 0; i < 8; ++i)                             \
        glds16(gB[i] + (size_t)kb1 * 2, (NXT) + b_lds_off[i]);                \
    SCHED0;                                                                   \
    const int ka2 = (((TS) + 2) < NT ? ((TS) + 2) : 0) * BK;                  \
    AL0 = __builtin_nontemporal_load((const f32x4*)(gA + ka2));               \
    AL1 = __builtin_nontemporal_load((const f32x4*)(gA + ka2) + 1);           \
    SCHED0;                                                                   \
    asm volatile("s_waitcnt lgkmcnt(0)" ::: "memory");                        \
    SCHED0;                                                                   \
    __builtin_amdgcn_s_setprio(1);                                            \
    _Pragma("unroll") for (int ak = 0; ak < 4; ++ak)                          \
        _Pragma("unroll") for (int af = 0; af < 2; ++af)                      \
            _Pragma("unroll") for (int bfi = 0; bfi < 2; ++bfi)               \
                acc[af][bfi] = __builtin_amdgcn_mfma_f32_16x16x32_bf16(       \
                    afr[af][ak], bfr[bfi][ak], acc[af][bfi], 0, 0, 0);        \
    __builtin_amdgcn_s_setprio(0);                                            \
    SCHED0;                                                                   \
    {                                                                         \
      bf16x8 pk;                                                              \
      _Pragma("unroll") for (int j = 0; j < 4; ++j) {                         \
        pk[j] = (bf16)AW0[j];                                                 \
        pk[j + 4] = (bf16)AW1[j];                                             \
      }                                                                       \
      *(bf16x8*)((NXT) + a_lds_off) = pk;                                     \
    }                                                                         \
    asm volatile("s_waitcnt vmcnt(2) lgkmcnt(0)" ::: "memory");               \
    SBAR;                                                                     \
    SCHED0;                                                                   \
  }

  for (int ts = 0; ts < NT; ts += 2) {
    BODY(ts, lds[0], lds[1], aS1a, aS1b, aS0a, aS0b);
    BODY(ts + 1, lds[1], lds[0], aS0a, aS0b, aS1a, aS1b);
  }
#undef BODY

  // ---- epilogue (C/D: col = lane&15, row = (lane>>4)*4 + reg)
#pragma unroll
  for (int af = 0; af < 2; ++af)
#pragma unroll
    for (int bfi = 0; bfi < 2; ++bfi) {
      const int mb = m0 + af * 16 + (l >> 4) * 4;
      const int n = w * 32 + bfi * 16 + (l & 15);
      f32x4 v = acc[af][bfi];
      if (SCALE) {
#pragma unroll
        for (int j = 0; j < 4; ++j) v[j] *= filt[mb + j];
      }
      if (OUTT) {
        bf16x4 pv;
#pragma unroll
        for (int j = 0; j < 4; ++j) pv[j] = (bf16)v[j];
        *(bf16x4*)((bf16*)outp + (size_t)n * MROWS + mb) = pv;
      } else {
        float* po = (float*)outp + (size_t)mb * NOUT + n;
#pragma unroll
        for (int j = 0; j < 4; ++j) po[(size_t)j * NOUT] = v[j];
      }
    }
}

// W [256][256] fp32 -> Wt [n][k] bf16 (transpose + convert)
__global__ void prep_wt(const float* __restrict__ W, bf16* __restrict__ Wt) {
  const int k = blockIdx.x;
  const int n = threadIdx.x;
  Wt[(size_t)n * 256 + k] = (bf16)W[(size_t)k * 256 + n];
}

extern "C" void kernel_launch(void* const* d_in, const int* in_sizes, int n_in,
                              void* d_out, int out_size, void* d_ws, size_t ws_size,
                              hipStream_t stream) {
  const float* features = (const float*)d_in[0];
  const float* wavelets = (const float*)d_in[1];
  const float* wavelets_inv = (const float*)d_in[2];
  const float* W = (const float*)d_in[3];
  const float* filt = (const float*)d_in[4];
  float* out = (float*)d_out;

  char* ws = (char*)d_ws;
  bf16* Wt = (bf16*)ws;                       // 128 KiB
  bf16* Tt = (bf16*)(ws + 131072);            // 4 MiB: (features@W)^T
  bf16* Ft = (bf16*)(ws + 131072 + 4194304);  // 4 MiB: (filt*spectral)^T

  prep_wt<<<256, 256, 0, stream>>>(W, Wt);
  gemm_fused<false, true><<<256, NTHREADS, 0, stream>>>(features, Wt, nullptr, Tt, 256, 256);
  gemm_fused<true, true><<<256, NTHREADS, 0, stream>>>(wavelets_inv, Tt, filt, Ft, 8192, 8192);
  gemm_fused<false, false><<<256, NTHREADS, 0, stream>>>(wavelets, Ft, nullptr, out, 8192, 8192);
}